// Round 10
// baseline (169.672 us; speedup 1.0000x reference)
//
#include <hip/hip_runtime.h>

#define BB 16
#define CC 80
#define DD 1024
#define HW 196
#define NSP (BB * HW)        // 3136 = 49 full waves, zero lane waste
#define NCH 8                // d-chunks of 128
#define DCH 128
#define CPB 8                // classes per scores block (halves img traffic vs 4)
#define NCQ (CC / CPB)       // 10 class-groups -> grid 1040 blocks
#define PG 16                // classes per pool block (4 per wave)
#define TWO_LOG2E 2.8853900817779268f

// ---------------- K1: scores + imgT side-product ----------------
// R5-proven structure; only CPB 4->8 (img re-read 20x -> 10x = 128 MB from
// L3; theory: scores_k is L3-BW-bound at ~4 TB/s, so traffic halving -> ~45us).
// Lane = flattened (b,hw). img chunk loaded 32 regs/quarter; word/fa uniform
// -> scalar pipe. Stores x = -2*log2e * sum_d fa[d]/(e^{2 img w}+1).
__global__ __launch_bounds__(256) void scores_k(const float* __restrict__ img,
                                                const float* __restrict__ word,
                                                const float* __restrict__ fa,
                                                float* __restrict__ partial,
                                                float* __restrict__ imgT) {
    const int g = blockIdx.x * 256 + threadIdx.x;
    if (g >= NSP) return;                           // wave-uniform exit
    const int b  = g / HW;
    const int hw = g - b * HW;
    const int d0 = blockIdx.y * DCH;
    const int c0 = blockIdx.z * CPB;

    const float* ip = img + ((size_t)b * DD + d0) * HW + hw;

    float p[CPB];
#pragma unroll
    for (int k = 0; k < CPB; ++k) p[k] = 0.f;

    for (int q = 0; q < DCH / 32; ++q) {            // 4 quarters of 32 d
        float iv[32];
        const float* qp = ip + (size_t)q * 32 * HW;
#pragma unroll
        for (int i = 0; i < 32; ++i)
            iv[i] = qp[(size_t)i * HW];

        if (blockIdx.z == 0) {                       // block-uniform branch
            float4* tp = (float4*)(imgT + (size_t)g * DD + d0 + q * 32);
#pragma unroll
            for (int i = 0; i < 8; ++i)
                tp[i] = make_float4(iv[4 * i], iv[4 * i + 1], iv[4 * i + 2], iv[4 * i + 3]);
        }

#pragma unroll
        for (int i = 0; i < 32; ++i)
            iv[i] *= TWO_LOG2E;                      // exp2(iv*w) == e^{2x}

        const float* fp = fa + d0 + q * 32;          // uniform -> SGPRs
#pragma unroll
        for (int k = 0; k < CPB; ++k) {
            const float* wp = word + (size_t)(c0 + k) * DD + d0 + q * 32;
            float p0 = 0.f, p1 = 0.f;
#pragma unroll
            for (int i = 0; i < 32; i += 2) {
                float y0 = iv[i]     * wp[i];
                float y1 = iv[i + 1] * wp[i + 1];
                float e0 = __builtin_amdgcn_exp2f(y0);
                float e1 = __builtin_amdgcn_exp2f(y1);
                float r0 = __builtin_amdgcn_rcpf(e0 + 1.f);
                float r1 = __builtin_amdgcn_rcpf(e1 + 1.f);
                p0 = fmaf(fp[i],     r0, p0);
                p1 = fmaf(fp[i + 1], r1, p1);
            }
            p[k] += p0 + p1;
        }
    }

#pragma unroll
    for (int k = 0; k < CPB; ++k)
        partial[(((size_t)b * NCH + blockIdx.y) * CC + (c0 + k)) * HW + hw]
            = (-TWO_LOG2E) * p[k];
}

// ---------------- K2: standalone softmax (R2-proven shape) ----------------
// Block per (b,c), 256 thr. Sums the 8 d-chunk partials, softmax via exp2.
// coef is ALIASED onto partial's ch=0 slice: this block is the unique
// reader of partial[b][*][c][*], and all its reads complete before the
// write (the LDS reduction's __syncthreads orders them). Saves 2.5 MB ws.
__global__ __launch_bounds__(256) void softmax_k(float* __restrict__ partial) {
    const int bc = blockIdx.x;
    const int b = bc / CC, c = bc - b * CC;
    const int t = threadIdx.x;

    float x = -3.4e38f;
    if (t < HW) {
        float P = 0.f;
#pragma unroll
        for (int ch = 0; ch < NCH; ++ch)
            P += partial[(((size_t)b * NCH + ch) * CC + c) * HW + t];
        x = P;                                       // already -2*log2e scaled
    }

    __shared__ float rmax[4], rsum[4];
    const int wv = t >> 6;

    float m = x;
#pragma unroll
    for (int off = 32; off >= 1; off >>= 1) m = fmaxf(m, __shfl_xor(m, off, 64));
    if ((t & 63) == 0) rmax[wv] = m;
    __syncthreads();
    m = fmaxf(fmaxf(rmax[0], rmax[1]), fmaxf(rmax[2], rmax[3]));

    float e = (t < HW) ? __builtin_amdgcn_exp2f(x - m) : 0.f;
    float s = e;
#pragma unroll
    for (int off = 32; off >= 1; off >>= 1) s += __shfl_xor(s, off, 64);
    if ((t & 63) == 0) rsum[wv] = s;
    __syncthreads();
    s = rsum[0] + rsum[1] + rsum[2] + rsum[3];

    if (t < HW)   // coef[b][c][t] aliases partial[b][0][c][t]
        partial[((size_t)b * NCH * CC + c) * HW + t] = e * __builtin_amdgcn_rcpf(s);
}

// ---------------- K3: pooling (pool3 phase-P, trivial coef staging) --------
// Grid (16 b, 8 d-tiles of 128, 5 c-groups of 16) = 640 blocks, 10 waves/CU.
// imgT re-read 5x = 64 MB. Phase S replaced by a flat 12.5 KB coef->LDS f4
// copy (R8's merged softmax was 128 scattered loads/thread, redundant x8).
// Phase P: thread = d-pair d0+2l (coalesced f2); wave = 4 classes; per
// h-quad: 4 f2 VMEM + 4 broadcast ds_read_b128 (conflict-free) + 32 v_fma.
__global__ __launch_bounds__(256) void pool4_k(const float* __restrict__ imgT,
                                               const float* __restrict__ partial,
                                               float* __restrict__ out) {
    __shared__ float ct[PG * HW];                 // 12544 B
    const int b  = blockIdx.x;
    const int d0 = blockIdx.y * 128;
    const int cg = blockIdx.z * PG;
    const int t  = threadIdx.x;
    const int w  = t >> 6, l = t & 63;

    // coef rows live at partial[b][0][c][:] (aliased by softmax_k)
    const float4* cs = (const float4*)(partial + ((size_t)b * NCH * CC + cg) * HW);
    float4* cd = (float4*)ct;
    for (int j = t; j < PG * HW / 4; j += 256) cd[j] = cs[j];
    __syncthreads();

    const float* ib  = imgT + (size_t)b * HW * DD + d0 + 2 * l;
    const float* cr0 = ct + (4 * w) * HW;

    float2 a0 = {0, 0}, a1 = {0, 0}, a2 = {0, 0}, a3 = {0, 0};
    for (int h = 0; h < HW; h += 4) {
        float2 i0 = *(const float2*)(ib + (size_t)(h    ) * DD);
        float2 i1 = *(const float2*)(ib + (size_t)(h + 1) * DD);
        float2 i2 = *(const float2*)(ib + (size_t)(h + 2) * DD);
        float2 i3 = *(const float2*)(ib + (size_t)(h + 3) * DD);
        float4 c0v = *(const float4*)(cr0 + h);               // broadcast b128
        float4 c1v = *(const float4*)(cr0 + HW + h);
        float4 c2v = *(const float4*)(cr0 + 2 * HW + h);
        float4 c3v = *(const float4*)(cr0 + 3 * HW + h);
#define ACC2(A, CV)                                                              \
        A.x = fmaf(CV.x, i0.x, fmaf(CV.y, i1.x, fmaf(CV.z, i2.x, fmaf(CV.w, i3.x, A.x)))); \
        A.y = fmaf(CV.x, i0.y, fmaf(CV.y, i1.y, fmaf(CV.z, i2.y, fmaf(CV.w, i3.y, A.y))));
        ACC2(a0, c0v)
        ACC2(a1, c1v)
        ACC2(a2, c2v)
        ACC2(a3, c3v)
#undef ACC2
    }

    float* ob = out + ((size_t)b * CC + cg + 4 * w) * DD + d0 + 2 * l;
    *(float2*)(ob)                  = a0;
    *(float2*)(ob + DD)             = a1;
    *(float2*)(ob + 2 * (size_t)DD) = a2;
    *(float2*)(ob + 3 * (size_t)DD) = a3;
}

extern "C" void kernel_launch(void* const* d_in, const int* in_sizes, int n_in,
                              void* d_out, int out_size, void* d_ws, size_t ws_size,
                              hipStream_t stream) {
    // inputs: [0]=batch_size(int,1) [1]=img [2]=word [3]=fc_a_w [4]=fc_a_b
    const float* img  = (const float*)d_in[1];
    const float* word = (const float*)d_in[2];
    const float* fa   = (const float*)d_in[3];
    float* out = (float*)d_out;

    // workspace (floats): partial[16][8][80][196] = 8.03 MB | imgT[3136][1024] = 12.85 MB
    float* partial = (float*)d_ws;
    float* imgT    = partial + (size_t)BB * NCH * CC * HW;

    scores_k<<<dim3((NSP + 255) / 256, NCH, NCQ), 256, 0, stream>>>(img, word, fa, partial, imgT);
    softmax_k<<<BB * CC, 256, 0, stream>>>(partial);
    pool4_k<<<dim3(BB, NCH, CC / PG), 256, 0, stream>>>(imgT, partial, out);
}

// Round 11
// 152.350 us; speedup vs baseline: 1.1137x; 1.1137x over previous
//
#include <hip/hip_runtime.h>

#define BB 16
#define CC 80
#define DD 1024
#define HW 196
#define NSP (BB * HW)        // 3136 = 49 full waves, zero lane waste
#define PG 16                // classes per pool block (4 per wave)
#define TWO_LOG2E 2.8853900817779268f

// ---------------- K1: scores + imgT side-product ----------------
// R5-proven inner structure (quarters of 32 d; word/fa -> scalar pipe).
// Templated on chunk count / classes-per-block so we can run the
// traffic-halved config (NCHT=16, CPBT=8 -> 2080 blocks, 128 MB img reads)
// with a proven fallback (NCHT=8, CPBT=4 -> 2080 blocks, 256 MB).
// Stores x = -2*log2e * sum_d fa[d]/(e^{2 img w}+1); affine remainder of the
// true score cancels in softmax; exp2(x) == softmax numerator pre-max.
template <int NCHT, int CPBT>
__global__ __launch_bounds__(256) void scores_k(const float* __restrict__ img,
                                                const float* __restrict__ word,
                                                const float* __restrict__ fa,
                                                float* __restrict__ partial,
                                                float* __restrict__ imgT) {
    constexpr int DCHT = DD / NCHT;                 // 64 or 128
    const int g = blockIdx.x * 256 + threadIdx.x;
    if (g >= NSP) return;                           // wave-uniform exit
    const int b  = g / HW;
    const int hw = g - b * HW;
    const int d0 = blockIdx.y * DCHT;
    const int c0 = blockIdx.z * CPBT;

    const float* ip = img + ((size_t)b * DD + d0) * HW + hw;

    float p[CPBT];
#pragma unroll
    for (int k = 0; k < CPBT; ++k) p[k] = 0.f;

    for (int q = 0; q < DCHT / 32; ++q) {           // quarters of 32 d
        float iv[32];
        const float* qp = ip + (size_t)q * 32 * HW;
#pragma unroll
        for (int i = 0; i < 32; ++i)
            iv[i] = qp[(size_t)i * HW];

        if (blockIdx.z == 0) {                       // block-uniform branch
            float4* tp = (float4*)(imgT + (size_t)g * DD + d0 + q * 32);
#pragma unroll
            for (int i = 0; i < 8; ++i)
                tp[i] = make_float4(iv[4 * i], iv[4 * i + 1], iv[4 * i + 2], iv[4 * i + 3]);
        }

#pragma unroll
        for (int i = 0; i < 32; ++i)
            iv[i] *= TWO_LOG2E;                      // exp2(iv*w) == e^{2x}

        const float* fp = fa + d0 + q * 32;          // uniform -> SGPRs
#pragma unroll
        for (int k = 0; k < CPBT; ++k) {
            const float* wp = word + (size_t)(c0 + k) * DD + d0 + q * 32;
            float p0 = 0.f, p1 = 0.f;
#pragma unroll
            for (int i = 0; i < 32; i += 2) {
                float y0 = iv[i]     * wp[i];
                float y1 = iv[i + 1] * wp[i + 1];
                float e0 = __builtin_amdgcn_exp2f(y0);
                float e1 = __builtin_amdgcn_exp2f(y1);
                float r0 = __builtin_amdgcn_rcpf(e0 + 1.f);
                float r1 = __builtin_amdgcn_rcpf(e1 + 1.f);
                p0 = fmaf(fp[i],     r0, p0);
                p1 = fmaf(fp[i + 1], r1, p1);
            }
            p[k] += p0 + p1;
        }
    }

#pragma unroll
    for (int k = 0; k < CPBT; ++k)
        partial[(((size_t)b * NCHT + blockIdx.y) * CC + (c0 + k)) * HW + hw]
            = (-TWO_LOG2E) * p[k];
}

// ---------------- K2: standalone softmax ----------------
// Block per (b,c). Sums NCHT d-chunk partials, softmax via exp2. coef is
// aliased onto partial's ch=0 slice (this block is the unique reader of
// partial[b][*][c][*]; reads complete before the write -- __syncthreads
// in the reduction orders them).
template <int NCHT>
__global__ __launch_bounds__(256) void softmax_k(float* __restrict__ partial) {
    const int bc = blockIdx.x;
    const int b = bc / CC, c = bc - b * CC;
    const int t = threadIdx.x;

    float x = -3.4e38f;
    if (t < HW) {
        float P = 0.f;
#pragma unroll
        for (int ch = 0; ch < NCHT; ++ch)
            P += partial[(((size_t)b * NCHT + ch) * CC + c) * HW + t];
        x = P;                                       // already -2*log2e scaled
    }

    __shared__ float rmax[4], rsum[4];
    const int wv = t >> 6;

    float m = x;
#pragma unroll
    for (int off = 32; off >= 1; off >>= 1) m = fmaxf(m, __shfl_xor(m, off, 64));
    if ((t & 63) == 0) rmax[wv] = m;
    __syncthreads();
    m = fmaxf(fmaxf(rmax[0], rmax[1]), fmaxf(rmax[2], rmax[3]));

    float e = (t < HW) ? __builtin_amdgcn_exp2f(x - m) : 0.f;
    float s = e;
#pragma unroll
    for (int off = 32; off >= 1; off >>= 1) s += __shfl_xor(s, off, 64);
    if ((t & 63) == 0) rsum[wv] = s;
    __syncthreads();
    s = rsum[0] + rsum[1] + rsum[2] + rsum[3];

    if (t < HW)   // coef[b][c][t] aliases partial[b][0][c][t]
        partial[((size_t)b * NCHT * CC + c) * HW + t] = e * __builtin_amdgcn_rcpf(s);
}

// ---------------- K3: pooling ----------------
// Grid (16 b, 16 d-tiles of 64, 5 c-groups of 16) = 1280 blocks x 4 waves
// = 20 waves/CU (pool4's 640 blocks = 2.5 blocks/CU was latency-starved).
// imgT traffic 5x = 64 MB; coef staging 16 MB. Thread owns d = d0 + lane
// (coalesced b32); wave owns 4 classes; per h-quad: 4 b32 VMEM + 4
// broadcast ds_read_b128 (same-address -> conflict-free) + 16 v_fma.
__global__ __launch_bounds__(256) void pool5_k(const float* __restrict__ imgT,
                                               const float* __restrict__ coefBase,
                                               size_t coefBStride,
                                               float* __restrict__ out) {
    __shared__ float ct[PG * HW];                 // 12544 B
    const int b  = blockIdx.x;
    const int d0 = blockIdx.y * 64;
    const int cg = blockIdx.z * PG;
    const int t  = threadIdx.x;
    const int w  = t >> 6, l = t & 63;

    // coef rows live at coefBase[b*coefBStride + c*HW]
    const float4* cs = (const float4*)(coefBase + (size_t)b * coefBStride + (size_t)cg * HW);
    float4* cd = (float4*)ct;
    for (int j = t; j < PG * HW / 4; j += 256) cd[j] = cs[j];
    __syncthreads();

    const float* ib  = imgT + (size_t)b * HW * DD + d0 + l;
    const float* cr0 = ct + (4 * w) * HW;

    float a0 = 0.f, a1 = 0.f, a2 = 0.f, a3 = 0.f;
    for (int h = 0; h < HW; h += 4) {
        float i0 = ib[(size_t)(h    ) * DD];
        float i1 = ib[(size_t)(h + 1) * DD];
        float i2 = ib[(size_t)(h + 2) * DD];
        float i3 = ib[(size_t)(h + 3) * DD];
        float4 c0v = *(const float4*)(cr0 + h);               // broadcast b128
        float4 c1v = *(const float4*)(cr0 + HW + h);
        float4 c2v = *(const float4*)(cr0 + 2 * HW + h);
        float4 c3v = *(const float4*)(cr0 + 3 * HW + h);
        a0 = fmaf(c0v.x, i0, fmaf(c0v.y, i1, fmaf(c0v.z, i2, fmaf(c0v.w, i3, a0))));
        a1 = fmaf(c1v.x, i0, fmaf(c1v.y, i1, fmaf(c1v.z, i2, fmaf(c1v.w, i3, a1))));
        a2 = fmaf(c2v.x, i0, fmaf(c2v.y, i1, fmaf(c2v.z, i2, fmaf(c2v.w, i3, a2))));
        a3 = fmaf(c3v.x, i0, fmaf(c3v.y, i1, fmaf(c3v.z, i2, fmaf(c3v.w, i3, a3))));
    }

    float* ob = out + ((size_t)b * CC + cg + 4 * w) * DD + d0 + l;
    ob[0]              = a0;
    ob[DD]             = a1;
    ob[2 * (size_t)DD] = a2;
    ob[3 * (size_t)DD] = a3;
}

extern "C" void kernel_launch(void* const* d_in, const int* in_sizes, int n_in,
                              void* d_out, int out_size, void* d_ws, size_t ws_size,
                              hipStream_t stream) {
    // inputs: [0]=batch_size(int,1) [1]=img [2]=word [3]=fc_a_w [4]=fc_a_b
    const float* img  = (const float*)d_in[1];
    const float* word = (const float*)d_in[2];
    const float* fa   = (const float*)d_in[3];
    float* out = (float*)d_out;

    const size_t imgT_elems = (size_t)NSP * DD;                 // 12.85 MB
    const size_t need16 = ((size_t)BB * 16 * CC * HW + imgT_elems) * sizeof(float); // 28.9 MB

    if (ws_size >= need16) {
        // traffic-halved config: NCH=16, CPB=8, NCQ=10 -> 2080 blocks, 128 MB
        float* partial = (float*)d_ws;                          // [16][16][80][196]
        float* imgT    = partial + (size_t)BB * 16 * CC * HW;
        scores_k<16, 8><<<dim3((NSP + 255) / 256, 16, CC / 8), 256, 0, stream>>>(
            img, word, fa, partial, imgT);
        softmax_k<16><<<BB * CC, 256, 0, stream>>>(partial);
        pool5_k<<<dim3(BB, DD / 64, CC / PG), 256, 0, stream>>>(
            imgT, partial, (size_t)16 * CC * HW, out);
    } else {
        // proven fallback: NCH=8, CPB=4, NCQ=20 -> 2080 blocks, 256 MB
        float* partial = (float*)d_ws;                          // [16][8][80][196]
        float* imgT    = partial + (size_t)BB * 8 * CC * HW;
        scores_k<8, 4><<<dim3((NSP + 255) / 256, 8, CC / 4), 256, 0, stream>>>(
            img, word, fa, partial, imgT);
        softmax_k<8><<<BB * CC, 256, 0, stream>>>(partial);
        pool5_k<<<dim3(BB, DD / 64, CC / PG), 256, 0, stream>>>(
            imgT, partial, (size_t)8 * CC * HW, out);
    }
}